// Round 6
// baseline (192.488 us; speedup 1.0000x reference)
//
#include <hip/hip_runtime.h>

// ClusterAssignment: q[n,k] = (1/(1+||z_n-c_k||^2)) / sum_k(...)
// N=65536, K=64, D=128, fp32. ALPHA=1.0 -> power = 1.
//
// Round 4 re-resubmit (rounds 4 & 5 both died to broker/container infra
// failures; this source has never been measured).
//   Round-3 post-mortem: launch_bounds(256,4) forced VGPR cap 128 < need
//   (~115 natural + epilogue) -> allocator spilled acc[] to scratch ->
//   WRITE_SIZE 200 MB (12x output). Also both prior rounds sat on an
//   LDS-issue wall (~41 us: 1 ds_read_b128 per 4 fma).
//   Fix: block = 4 waves x 64 lanes; wave w owns feature chunk w (32 feats)
//   for all 64 rows (lane = row). Centroid addresses are then WAVE-UNIFORM
//   (chunk hoisted to SGPR via readfirstlane) -> compiler emits s_load
//   (scalar pipe): zero LDS, zero per-lane vmem in the hot loop.
//   Cross-wave reduce: ds_add_f32 into acc_lds[row][k], row-stride 65
//   (odd -> banks (lane+k)%32, 2 lanes/bank = free). 1+||c_k||^2 computed
//   once per block by wave 0 into b_lds. Finalize: each thread redundantly
//   rcp-sums its row (cheap), writes its wave's 16-cluster quarter.
//   Plain __launch_bounds__(256): no VGPR cap -> no spill; ~115 VGPR ->
//   4 waves/SIMD (grid-limited anyway: 1024 blocks x 4 waves = 16/CU).

constexpr int K_CL = 64;
constexpr int D_FT = 128;
constexpr int PADK = 65;   // 64 dot columns + 1 znorm column; odd stride

__global__ __launch_bounds__(256) void cluster_assign_kernel(
    const float* __restrict__ z,
    const float* __restrict__ cent,
    float* __restrict__ out)
{
    __shared__ float acc_lds[64 * PADK];   // [row][k], 16640 B
    __shared__ float b_lds[K_CL];          // 1 + ||c_k||^2

    const int tid   = threadIdx.x;
    const int wave  = tid >> 6;
    const int lane  = tid & 63;
    const int chunk = __builtin_amdgcn_readfirstlane(wave);  // SGPR, uniform

    // ---- zero the accumulator buffer (17 b32 stores/thread)
    for (int i = tid; i < 64 * PADK; i += 256) acc_lds[i] = 0.f;

    const int row = blockIdx.x * 64 + lane;

    // ---- this wave's 32-feature z slice for its row: 8 float4 in VGPRs
    const float4* zp =
        reinterpret_cast<const float4*>(z + (size_t)row * D_FT) + chunk * 8;
    float4 zv[8];
    #pragma unroll
    for (int j = 0; j < 8; ++j) zv[j] = zp[j];

    // ---- wave 0 additionally computes b_k = 1 + ||c_k||^2 (once per block)
    if (wave == 0) {
        const float4* cp = reinterpret_cast<const float4*>(cent) + lane * 32;
        float4 s4 = {0.f, 0.f, 0.f, 0.f};
        #pragma unroll
        for (int j = 0; j < 32; ++j) {
            float4 c = cp[j];
            s4.x = fmaf(c.x, c.x, s4.x);
            s4.y = fmaf(c.y, c.y, s4.y);
            s4.z = fmaf(c.z, c.z, s4.z);
            s4.w = fmaf(c.w, c.w, s4.w);
        }
        b_lds[lane] = 1.f + ((s4.x + s4.y) + (s4.z + s4.w));
    }

    // ---- znorm partial over this chunk
    float znp = 0.f;
    #pragma unroll
    for (int j = 0; j < 8; ++j) {
        znp = fmaf(zv[j].x, zv[j].x, znp);
        znp = fmaf(zv[j].y, zv[j].y, znp);
        znp = fmaf(zv[j].z, zv[j].z, znp);
        znp = fmaf(zv[j].w, zv[j].w, znp);
    }

    // ---- dot partials: centroid loads are wave-uniform -> scalar loads.
    //      4 independent fma chains per k; acc[64] stays in VGPRs.
    const float4* cw = reinterpret_cast<const float4*>(cent) + chunk * 8;
    float acc[K_CL];
    #pragma unroll 2
    for (int k = 0; k < K_CL; ++k) {
        const float4* cp = cw + k * 32;   // uniform address (k, chunk uniform)
        float4 d = {0.f, 0.f, 0.f, 0.f};
        #pragma unroll
        for (int j = 0; j < 8; ++j) {
            float4 c = cp[j];
            d.x = fmaf(c.x, zv[j].x, d.x);
            d.y = fmaf(c.y, zv[j].y, d.y);
            d.z = fmaf(c.z, zv[j].z, d.z);
            d.w = fmaf(c.w, zv[j].w, d.w);
        }
        acc[k] = (d.x + d.y) + (d.z + d.w);
    }

    __syncthreads();   // zero-init (and b_lds) complete before any ds_add

    // ---- cross-wave reduction: conflict-free ds_add_f32 (banks (lane+k)%32)
    float* myrow = &acc_lds[lane * PADK];
    #pragma unroll
    for (int k = 0; k < K_CL; ++k)
        __hip_atomic_fetch_add(&myrow[k], acc[k],
                               __ATOMIC_RELAXED, __HIP_MEMORY_SCOPE_WORKGROUP);
    __hip_atomic_fetch_add(&myrow[K_CL], znp,
                           __ATOMIC_RELAXED, __HIP_MEMORY_SCOPE_WORKGROUP);

    __syncthreads();

    // ---- finalize: each thread sums its row (redundant x4, cheap),
    //      writes its wave's 16-cluster quarter.
    const float znorm = myrow[K_CL];
    float ssum = 0.f;
    #pragma unroll
    for (int k = 0; k < K_CL; ++k) {
        float d1 = fmaf(-2.f, myrow[k], znorm + b_lds[k]);  // 1 + ||z-c||^2
        ssum += __builtin_amdgcn_rcpf(d1);
    }
    const float inv = __builtin_amdgcn_rcpf(ssum);

    const int kbase = wave * 16;
    float4* op = reinterpret_cast<float4*>(out + (size_t)row * K_CL + kbase);
    #pragma unroll
    for (int q = 0; q < 4; ++q) {
        const float* mr = myrow + kbase + q * 4;
        const float* bb = b_lds + kbase + q * 4;
        float4 o;
        o.x = __builtin_amdgcn_rcpf(fmaf(-2.f, mr[0], znorm + bb[0])) * inv;
        o.y = __builtin_amdgcn_rcpf(fmaf(-2.f, mr[1], znorm + bb[1])) * inv;
        o.z = __builtin_amdgcn_rcpf(fmaf(-2.f, mr[2], znorm + bb[2])) * inv;
        o.w = __builtin_amdgcn_rcpf(fmaf(-2.f, mr[3], znorm + bb[3])) * inv;
        op[q] = o;
    }
}

extern "C" void kernel_launch(void* const* d_in, const int* in_sizes, int n_in,
                              void* d_out, int out_size, void* d_ws, size_t ws_size,
                              hipStream_t stream) {
    const float* z    = (const float*)d_in[0];
    const float* cent = (const float*)d_in[1];
    float* out        = (float*)d_out;

    dim3 grid(65536 / 64);   // 1024 blocks; 64 rows/block, 4 waves (chunks)
    cluster_assign_kernel<<<grid, dim3(256), 0, stream>>>(z, cent, out);
}

// Round 7
// 176.074 us; speedup vs baseline: 1.0932x; 1.0932x over previous
//
#include <hip/hip_runtime.h>

// ClusterAssignment: q[n,k] = (1/(1+||z_n-c_k||^2)) / sum_k(...)
// N=65536, K=64, D=128, fp32. ALPHA=1.0 -> power = 1.
//
// Round 7: round-6 structure, spill fixed.
//   Round-6 post-mortem: WRITE_SIZE 80 MB = output 16.4 MB + acc[64] scratch
//   (64 MB). Cause: "#pragma unroll 2" left k runtime -> acc[k] runtime-
//   indexed -> localMem (rule #20), NOT a launch-bounds issue (VGPR=76,
//   uncapped). Fix: FULL unroll -> static indices -> regs/AGPRs (round 1
//   proved this exact pattern compiles spill-free).
//   Structure: block = 4 waves x 64 lanes; wave w owns feature chunk w
//   (32 feats) for all 64 rows (lane = row). Centroid addresses wave-uniform
//   (chunk in SGPR via readfirstlane) -> scalar s_load pipe, overlaps VALU;
//   hot loop has zero LDS and zero per-lane vmem. Cross-wave reduce:
//   ds_add_f32 into acc_lds[row][k], row-stride 65 (banks (lane+k)%32,
//   2 lanes/bank = free). Plain __launch_bounds__(256): no VGPR cap.

constexpr int K_CL = 64;
constexpr int D_FT = 128;
constexpr int PADK = 65;   // 64 dot columns + 1 znorm column; odd stride

__global__ __launch_bounds__(256) void cluster_assign_kernel(
    const float* __restrict__ z,
    const float* __restrict__ cent,
    float* __restrict__ out)
{
    __shared__ float acc_lds[64 * PADK];   // [row][k], 16640 B
    __shared__ float b_lds[K_CL];          // 1 + ||c_k||^2

    const int tid   = threadIdx.x;
    const int wave  = tid >> 6;
    const int lane  = tid & 63;
    const int chunk = __builtin_amdgcn_readfirstlane(wave);  // SGPR, uniform

    // ---- zero the accumulator buffer (17 b32 stores/thread)
    for (int i = tid; i < 64 * PADK; i += 256) acc_lds[i] = 0.f;

    const int row = blockIdx.x * 64 + lane;

    // ---- this wave's 32-feature z slice for its row: 8 float4 in VGPRs
    const float4* zp =
        reinterpret_cast<const float4*>(z + (size_t)row * D_FT) + chunk * 8;
    float4 zv[8];
    #pragma unroll
    for (int j = 0; j < 8; ++j) zv[j] = zp[j];

    // ---- wave 0 additionally computes b_k = 1 + ||c_k||^2 (once per block)
    if (wave == 0) {
        const float4* cp = reinterpret_cast<const float4*>(cent) + lane * 32;
        float4 s4 = {0.f, 0.f, 0.f, 0.f};
        #pragma unroll
        for (int j = 0; j < 32; ++j) {
            float4 c = cp[j];
            s4.x = fmaf(c.x, c.x, s4.x);
            s4.y = fmaf(c.y, c.y, s4.y);
            s4.z = fmaf(c.z, c.z, s4.z);
            s4.w = fmaf(c.w, c.w, s4.w);
        }
        b_lds[lane] = 1.f + ((s4.x + s4.y) + (s4.z + s4.w));
    }

    // ---- znorm partial over this chunk
    float znp = 0.f;
    #pragma unroll
    for (int j = 0; j < 8; ++j) {
        znp = fmaf(zv[j].x, zv[j].x, znp);
        znp = fmaf(zv[j].y, zv[j].y, znp);
        znp = fmaf(zv[j].z, zv[j].z, znp);
        znp = fmaf(zv[j].w, zv[j].w, znp);
    }

    // ---- dot partials: FULL unroll (static acc indices -> registers).
    //      Centroid loads wave-uniform -> s_load; 4 indep fma chains per k.
    const float4* cw = reinterpret_cast<const float4*>(cent) + chunk * 8;
    float acc[K_CL];
    #pragma unroll
    for (int k = 0; k < K_CL; ++k) {
        const float4* cp = cw + k * 32;   // uniform address (k literal)
        float4 d = {0.f, 0.f, 0.f, 0.f};
        #pragma unroll
        for (int j = 0; j < 8; ++j) {
            float4 c = cp[j];
            d.x = fmaf(c.x, zv[j].x, d.x);
            d.y = fmaf(c.y, zv[j].y, d.y);
            d.z = fmaf(c.z, zv[j].z, d.z);
            d.w = fmaf(c.w, zv[j].w, d.w);
        }
        acc[k] = (d.x + d.y) + (d.z + d.w);
    }

    __syncthreads();   // zero-init (and b_lds) complete before any ds_add

    // ---- cross-wave reduction: conflict-free ds_add_f32 (banks (lane+k)%32)
    float* myrow = &acc_lds[lane * PADK];
    #pragma unroll
    for (int k = 0; k < K_CL; ++k)
        __hip_atomic_fetch_add(&myrow[k], acc[k],
                               __ATOMIC_RELAXED, __HIP_MEMORY_SCOPE_WORKGROUP);
    __hip_atomic_fetch_add(&myrow[K_CL], znp,
                           __ATOMIC_RELAXED, __HIP_MEMORY_SCOPE_WORKGROUP);

    __syncthreads();

    // ---- finalize: each thread sums its row (redundant x4, cheap),
    //      writes its wave's 16-cluster quarter.
    const float znorm = myrow[K_CL];
    float ssum = 0.f;
    #pragma unroll
    for (int k = 0; k < K_CL; ++k) {
        float d1 = fmaf(-2.f, myrow[k], znorm + b_lds[k]);  // 1 + ||z-c||^2
        ssum += __builtin_amdgcn_rcpf(d1);
    }
    const float inv = __builtin_amdgcn_rcpf(ssum);

    const int kbase = wave * 16;
    float4* op = reinterpret_cast<float4*>(out + (size_t)row * K_CL + kbase);
    #pragma unroll
    for (int q = 0; q < 4; ++q) {
        const float* mr = myrow + kbase + q * 4;
        const float* bb = b_lds + kbase + q * 4;
        float4 o;
        o.x = __builtin_amdgcn_rcpf(fmaf(-2.f, mr[0], znorm + bb[0])) * inv;
        o.y = __builtin_amdgcn_rcpf(fmaf(-2.f, mr[1], znorm + bb[1])) * inv;
        o.z = __builtin_amdgcn_rcpf(fmaf(-2.f, mr[2], znorm + bb[2])) * inv;
        o.w = __builtin_amdgcn_rcpf(fmaf(-2.f, mr[3], znorm + bb[3])) * inv;
        op[q] = o;
    }
}

extern "C" void kernel_launch(void* const* d_in, const int* in_sizes, int n_in,
                              void* d_out, int out_size, void* d_ws, size_t ws_size,
                              hipStream_t stream) {
    const float* z    = (const float*)d_in[0];
    const float* cent = (const float*)d_in[1];
    float* out        = (float*)d_out;

    dim3 grid(65536 / 64);   // 1024 blocks; 64 rows/block, 4 waves (chunks)
    cluster_assign_kernel<<<grid, dim3(256), 0, stream>>>(z, cent, out);
}

// Round 10
// 79.358 us; speedup vs baseline: 2.4256x; 2.2187x over previous
//
#include <hip/hip_runtime.h>
#include <hip/hip_bf16.h>

// ClusterAssignment: q[n,k] = (1/(1+||z_n-c_k||^2)) / sum_k(...)
// N=65536, K=64, D=128, fp32. ALPHA=1.0 -> power = 1.
//
// Round 8 re-resubmit (rounds 8 & 9 both died to broker/container infra;
// this MFMA source has never been measured).
// MFMA (bf16 inputs, fp32 accum). The op is a 65536x64x128 GEMM
// (0.13 us of matrix pipe) + cheap epilogue -> memory-bound (~7.6 us floor).
// Round-7 post-mortem: scalar s_load path stalls on lgkmcnt(0) drains
// (SMEM unordered, 2-deep pipelining at SGPR=48) -> 85% stall; vector/LDS
// path has a ~35 us ds_read-issue wall. MFMA sidesteps both.
// Numerics: ||z-c||^2 = znorm + cnorm - 2 z.c with znorm/cnorm fp32-exact;
// only the dot is bf16 (err ~0.04 on dist ~257 -> dq ~1e-5 << 6e-4 thr).
//
// Layout (mfma_f32_16x16x32_bf16, m89-verified):
//   A: lane holds z[row=lane&15][k = kk*32 + (lane>>4)*8 + j], j=0..7
//   B: lane holds c[n  =lane&15+nt*16][k = kk*32 + (lane>>4)*8 + j]
//   C/D: col = lane&15 (+16*nt), row = (lane>>4)*4 + reg
// Per wave: 16 rows x 64 clusters = 4 N-tiles x 4 K-steps = 16 MFMA.
// Grid 512 x 256 thr (4 waves): 8 waves/CU, 2 tiles/wave (setup amortized).
// LDS: centroids bf16, row stride 136 (272 B): B-frag ds_read_b128 banks
// (4n+16kk)%32, n vs n+8 collide 2-way only = free (m136).

using bf16x8 = __attribute__((ext_vector_type(8))) __bf16;
using f32x4  = __attribute__((ext_vector_type(4))) float;

constexpr int K_CL = 64;
constexpr int D_FT = 128;
constexpr int CSTR = 136;   // padded bf16 row stride (272 B, 16B-aligned)

__global__ __launch_bounds__(256) void cluster_assign_mfma(
    const float* __restrict__ z,
    const float* __restrict__ cent,
    float* __restrict__ out)
{
    __shared__ __bf16 c_bf[K_CL * CSTR];   // 17408 B
    __shared__ float  b_lds[K_CL];         // 1 + ||c_k||^2

    const int tid  = threadIdx.x;
    const int wave = tid >> 6;
    const int lane = tid & 63;
    const int lo   = lane & 15;
    const int g    = lane >> 4;

    // ---- stage centroids to LDS as bf16 (coop: 8 float4/thread) + b_lds init
    {
        const float4* c4 = reinterpret_cast<const float4*>(cent);
        #pragma unroll
        for (int i = 0; i < 8; ++i) {
            int f   = tid + i * 256;       // float4 idx 0..2047
            int row = f >> 5;
            int c4i = f & 31;
            float4 v = c4[f];
            __bf16* dst = &c_bf[row * CSTR + c4i * 4];
            dst[0] = (__bf16)v.x; dst[1] = (__bf16)v.y;
            dst[2] = (__bf16)v.z; dst[3] = (__bf16)v.w;
        }
        if (tid < K_CL) b_lds[tid] = 1.0f;
    }
    __syncthreads();

    // ---- cnorm (fp32-exact from global, L2-hot): cluster tid&63, quarter tid>>6
    {
        int c = tid & 63, q = tid >> 6;
        const float4* p = reinterpret_cast<const float4*>(cent + c * D_FT + q * 32);
        float s = 0.f;
        #pragma unroll
        for (int j = 0; j < 8; ++j) {
            float4 v = p[j];
            s = fmaf(v.x, v.x, s); s = fmaf(v.y, v.y, s);
            s = fmaf(v.z, v.z, s); s = fmaf(v.w, v.w, s);
        }
        __hip_atomic_fetch_add(&b_lds[c], s,
                               __ATOMIC_RELAXED, __HIP_MEMORY_SCOPE_WORKGROUP);
    }

    // ---- B fragments (loop-invariant): 16x ds_read_b128 from c_bf
    bf16x8 bf[4][4];
    #pragma unroll
    for (int nt = 0; nt < 4; ++nt)
        #pragma unroll
        for (int kk = 0; kk < 4; ++kk)
            bf[nt][kk] = *reinterpret_cast<const bf16x8*>(
                &c_bf[(lo + nt * 16) * CSTR + kk * 32 + g * 8]);

    __syncthreads();   // b_lds final

    float bmine[4];
    #pragma unroll
    for (int nt = 0; nt < 4; ++nt) bmine[nt] = b_lds[lo + nt * 16];

    for (int it = 0; it < 2; ++it) {
        const int rowbase = blockIdx.x * 128 + it * 64 + wave * 16;

        // ---- load this lane's 32 z floats (row lo, k-chunks per kk)
        const char* zb = reinterpret_cast<const char*>(z)
                       + (size_t)(rowbase + lo) * 512 + g * 32;
        float4 zst[8];
        #pragma unroll
        for (int kk = 0; kk < 4; ++kk) {
            zst[2*kk]   = *reinterpret_cast<const float4*>(zb + kk * 128);
            zst[2*kk+1] = *reinterpret_cast<const float4*>(zb + kk * 128 + 16);
        }

        // ---- znorm (fp32-exact): partial over 32, reduce over g-groups
        float zn = 0.f;
        #pragma unroll
        for (int j = 0; j < 8; ++j) {
            float4 v = zst[j];
            zn = fmaf(v.x, v.x, zn); zn = fmaf(v.y, v.y, zn);
            zn = fmaf(v.z, v.z, zn); zn = fmaf(v.w, v.w, zn);
        }
        zn += __shfl_xor(zn, 16);
        zn += __shfl_xor(zn, 32);   // zn = ||z_row(lo)||^2 on all lanes

        // ---- pack A fragments (bf16 RNE; compiler pairs into cvt_pk)
        bf16x8 af[4];
        #pragma unroll
        for (int kk = 0; kk < 4; ++kk) {
            float4 u = zst[2*kk], v = zst[2*kk+1];
            bf16x8 a;
            a[0] = (__bf16)u.x; a[1] = (__bf16)u.y;
            a[2] = (__bf16)u.z; a[3] = (__bf16)u.w;
            a[4] = (__bf16)v.x; a[5] = (__bf16)v.y;
            a[6] = (__bf16)v.z; a[7] = (__bf16)v.w;
            af[kk] = a;
        }

        // ---- 16 MFMA: 4 N-tiles x 4 K-steps
        f32x4 acc[4] = {{0,0,0,0},{0,0,0,0},{0,0,0,0},{0,0,0,0}};
        #pragma unroll
        for (int kk = 0; kk < 4; ++kk)
            #pragma unroll
            for (int nt = 0; nt < 4; ++nt)
                acc[nt] = __builtin_amdgcn_mfma_f32_16x16x32_bf16(
                              af[kk], bf[nt][kk], acc[nt], 0, 0, 0);

        // ---- znorm for my 4 C-rows (C row = g*4+r, held as znorm[lane&15])
        float znr[4];
        #pragma unroll
        for (int r = 0; r < 4; ++r) znr[r] = __shfl(zn, g * 4 + r);

        // ---- numerators + row sums (16-lane shfl_xor reduce)
        float num[4][4];
        float psum[4] = {0.f, 0.f, 0.f, 0.f};
        #pragma unroll
        for (int nt = 0; nt < 4; ++nt)
            #pragma unroll
            for (int r = 0; r < 4; ++r) {
                float d1 = fmaf(-2.f, acc[nt][r], znr[r] + bmine[nt]);
                float nv = __builtin_amdgcn_rcpf(d1);   // 1/(1+dist)
                num[nt][r] = nv;
                psum[r] += nv;
            }
        #pragma unroll
        for (int r = 0; r < 4; ++r) {
            psum[r] += __shfl_xor(psum[r], 1);
            psum[r] += __shfl_xor(psum[r], 2);
            psum[r] += __shfl_xor(psum[r], 4);
            psum[r] += __shfl_xor(psum[r], 8);
            psum[r] = __builtin_amdgcn_rcpf(psum[r]);
        }

        // ---- store: row = rowbase + g*4 + r, col = lo + nt*16
        #pragma unroll
        for (int nt = 0; nt < 4; ++nt)
            #pragma unroll
            for (int r = 0; r < 4; ++r)
                out[(size_t)(rowbase + g * 4 + r) * K_CL + lo + nt * 16]
                    = num[nt][r] * psum[r];
    }
}

extern "C" void kernel_launch(void* const* d_in, const int* in_sizes, int n_in,
                              void* d_out, int out_size, void* d_ws, size_t ws_size,
                              hipStream_t stream) {
    const float* z    = (const float*)d_in[0];
    const float* cent = (const float*)d_in[1];
    float* out        = (float*)d_out;

    dim3 grid(65536 / 128);   // 512 blocks; 128 rows/block (4 waves x 16 x 2)
    cluster_assign_mfma<<<grid, dim3(256), 0, stream>>>(z, cent, out);
}